// Round 21
// baseline (343.610 us; speedup 1.0000x reference)
//
#include <hip/hip_runtime.h>
#include <stdint.h>

#define B_ROWS 16384
#define NIN    784
#define NH     500
#define NHP    512
#define NOUT   10
#define STEPS  25

// Verified reference semantics (R15 PASS):
//   fc1: per (row,n): f32 fmaf chains ascending k, k-blocks [0,512)+[512,784),
//        combined by one __fadd_rn; + b1 via one __fadd_rn.
//   LIF (both layers), per-op f32: m = fsub(fadd(fmul(0.95f,m),c),reset); spike = m>1
//   fc2: single ascending-h conditional-fadd chain (== fmaf(bit,w,acc)), + b2, LIF2.

// ---------------- K0: w1[500][784] -> k-blocked w1tb[k/4][512][4] ----------------
__global__ __launch_bounds__(256) void k0_wtrans(
    const float* __restrict__ w1, float* __restrict__ w1tb)
{
    const int i  = blockIdx.x * 256 + threadIdx.x;
    const int u  = i & 511;
    const int kb = i >> 9;
    if (kb >= 196) return;
    float4 v = make_float4(0.f, 0.f, 0.f, 0.f);
    if (u < NH) v = *(const float4*)(w1 + (size_t)u * NIN + kb * 4);
    *(float4*)(w1tb + (size_t)kb * 2048 + u * 4) = v;
}

// ---------------- K1: fc1 + LIF1 -> masks[row][512] ----------------
// lane = unit (t, t+256). x staged ONCE per 16-row tile in LDS (50 KB, one
// barrier); hot loop = ds_read_b128 broadcast (lgkmcnt, in-order) + prefetched
// coalesced w float4 (vmcnt, in-order) + 128 fmaf. No s_loads in loop.
// 512 blocks x 2 tiles = exactly 2 blocks/CU, zero tail.

#define K1_R 16

__global__ __launch_bounds__(256) void k1_fc1(
    const float* __restrict__ x, const float* __restrict__ w1tb,
    const float* __restrict__ b1, uint32_t* __restrict__ masks_g)
{
    __shared__ alignas(16) float xs[K1_R][NIN];   // 50,176 B
    const int t = threadIdx.x;

    for (int tile = 0; tile < 2; ++tile) {
        const int row0 = (blockIdx.x * 2 + tile) * K1_R;

        __syncthreads();                           // tile>0: prior reads done
        for (int i = t; i < K1_R * (NIN / 4); i += 256) {
            const int r = i / (NIN / 4), q = i - r * (NIN / 4);
            *(float4*)&xs[r][q * 4] =
                *(const float4*)(x + (size_t)(row0 + r) * NIN + q * 4);
        }
        __syncthreads();

        float accA[2][K1_R], accB[2][K1_R];
#pragma unroll
        for (int u = 0; u < 2; ++u)
#pragma unroll
            for (int r = 0; r < K1_R; ++r) { accA[u][r] = 0.f; accB[u][r] = 0.f; }

        float4 wc0 = *(const float4*)(w1tb + (size_t)0 * 2048 + t * 4);
        float4 wc1 = *(const float4*)(w1tb + (size_t)0 * 2048 + (t + 256) * 4);

        // phase A: kb 0..127  (k in [0,512), BLIS block 1)
        for (int kb = 0; kb < 128; ++kb) {
            const float4 wn0 = *(const float4*)(w1tb + (size_t)(kb + 1) * 2048 + t * 4);
            const float4 wn1 = *(const float4*)(w1tb + (size_t)(kb + 1) * 2048 + (t + 256) * 4);
#pragma unroll
            for (int r = 0; r < K1_R; ++r) {
                const float4 xv = *(const float4*)&xs[r][kb * 4];  // broadcast
                accA[0][r] = fmaf(xv.x, wc0.x, accA[0][r]);        // ascending k
                accA[0][r] = fmaf(xv.y, wc0.y, accA[0][r]);
                accA[0][r] = fmaf(xv.z, wc0.z, accA[0][r]);
                accA[0][r] = fmaf(xv.w, wc0.w, accA[0][r]);
                accA[1][r] = fmaf(xv.x, wc1.x, accA[1][r]);
                accA[1][r] = fmaf(xv.y, wc1.y, accA[1][r]);
                accA[1][r] = fmaf(xv.z, wc1.z, accA[1][r]);
                accA[1][r] = fmaf(xv.w, wc1.w, accA[1][r]);
            }
            wc0 = wn0; wc1 = wn1;
        }
        // phase B: kb 128..195  (k in [512,784), BLIS block 2)
        for (int kb = 128; kb < 196; ++kb) {
            float4 wn0, wn1;
            const bool pf = (kb < 195);
            if (pf) {
                wn0 = *(const float4*)(w1tb + (size_t)(kb + 1) * 2048 + t * 4);
                wn1 = *(const float4*)(w1tb + (size_t)(kb + 1) * 2048 + (t + 256) * 4);
            }
#pragma unroll
            for (int r = 0; r < K1_R; ++r) {
                const float4 xv = *(const float4*)&xs[r][kb * 4];
                accB[0][r] = fmaf(xv.x, wc0.x, accB[0][r]);
                accB[0][r] = fmaf(xv.y, wc0.y, accB[0][r]);
                accB[0][r] = fmaf(xv.z, wc0.z, accB[0][r]);
                accB[0][r] = fmaf(xv.w, wc0.w, accB[0][r]);
                accB[1][r] = fmaf(xv.x, wc1.x, accB[1][r]);
                accB[1][r] = fmaf(xv.y, wc1.y, accB[1][r]);
                accB[1][r] = fmaf(xv.z, wc1.z, accB[1][r]);
                accB[1][r] = fmaf(xv.w, wc1.w, accB[1][r]);
            }
            if (pf) { wc0 = wn0; wc1 = wn1; }
        }

#pragma unroll
        for (int uu = 0; uu < 2; ++uu) {
            const int u = t + uu * 256;
            if (u >= NH) continue;
            const float bb = b1[u];
#pragma unroll
            for (int r = 0; r < K1_R; ++r) {
                const float dot = __fadd_rn(accA[uu][r], accB[uu][r]); // combine blocks
                const float c   = __fadd_rn(dot, bb);                  // + bias
                float m = 0.f;
                uint32_t bits = 0;
#pragma unroll
                for (int st = 0; st < STEPS; ++st) {
                    const float rs = (m > 1.0f) ? 1.0f : 0.0f;         // reset from PREV mem
                    m = __fsub_rn(__fadd_rn(__fmul_rn(0.95f, m), c), rs);
                    bits |= ((m > 1.0f) ? 1u : 0u) << st;
                }
                masks_g[(size_t)(row0 + r) * NHP + u] = bits;          // coalesced
            }
        }
    }
}

// ---------------- K2: fc2 + LIF2 -> outputs ----------------
// Thread = (row, step); masks read as uint4 (1 b128 per 4 h, 4-deep decode ILP).
// Chain per (row,o,st) stays ascending h. Scan phase per (row,o).

#define K2_RPB 10

__global__ __launch_bounds__(256) void k2_fc2(
    const uint32_t* __restrict__ masks_g, const float* __restrict__ w2,
    const float* __restrict__ b2, float* __restrict__ out)
{
    __shared__ float w2s[NH][NOUT];               // 20,000 B
    __shared__ float b2s[NOUT];
    __shared__ float c2[K2_RPB][NOUT][STEPS + 1]; // 10,400 B

    const int t    = threadIdx.x;
    const int row0 = blockIdx.x * K2_RPB;

    for (int i = t; i < NH * NOUT; i += 256) {
        const int h = i / NOUT, o = i - h * NOUT;
        w2s[h][o] = w2[o * NH + h];
    }
    if (t < NOUT) b2s[t] = b2[t];
    __syncthreads();

    const int rl = t / STEPS;                     // 0..9 (t<250)
    const int st = t - rl * STEPS;                // 0..24
    const int row = row0 + rl;

    if (t < K2_RPB * STEPS && row < B_ROWS) {
        float a[NOUT];
#pragma unroll
        for (int o = 0; o < NOUT; ++o) a[o] = 0.f;
        const uint4* m4 = (const uint4*)(masks_g + (size_t)row * NHP);
        for (int hq = 0; hq < NH / 4; ++hq) {     // 125 x uint4
            const uint4 q = m4[hq];
            const uint32_t mw[4] = {q.x, q.y, q.z, q.w};
#pragma unroll
            for (int cc = 0; cc < 4; ++cc) {      // h = 4*hq+cc ascending
                const float s = (float)((mw[cc] >> st) & 1u);
                const float* wp = &w2s[4 * hq + cc][0];
#pragma unroll
                for (int o = 0; o < NOUT; ++o)
                    a[o] = fmaf(s, wp[o], a[o]);  // exact conditional-fadd chain
            }
        }
#pragma unroll
        for (int o = 0; o < NOUT; ++o) c2[rl][o][st] = a[o];
    }
    __syncthreads();

    if (t < K2_RPB * NOUT) {                      // scan phase: (row, o)
        const int r2 = t / NOUT, o = t - r2 * NOUT;
        const int row2 = row0 + r2;
        if (row2 < B_ROWS) {
            float* spk_out = out;
            float* mem_out = out + (size_t)STEPS * B_ROWS * NOUT;
            const size_t base = (size_t)row2 * NOUT + o;
            const float bo = b2s[o];
            float m = 0.f;
#pragma unroll
            for (int s2 = 0; s2 < STEPS; ++s2) {
                const float c  = __fadd_rn(c2[r2][o][s2], bo);    // chain + bias
                const float rs = (m > 1.0f) ? 1.0f : 0.0f;        // reset from PREV mem
                m = __fsub_rn(__fadd_rn(__fmul_rn(0.95f, m), c), rs);
                const size_t idx = (size_t)s2 * (B_ROWS * NOUT) + base;
                spk_out[idx] = (m > 1.0f) ? 1.0f : 0.0f;
                mem_out[idx] = m;
            }
        }
    }
}

extern "C" void kernel_launch(void* const* d_in, const int* in_sizes, int n_in,
                              void* d_out, int out_size, void* d_ws, size_t ws_size,
                              hipStream_t stream)
{
    const float* x  = (const float*)d_in[0];
    const float* w1 = (const float*)d_in[1];
    const float* b1 = (const float*)d_in[2];
    const float* w2 = (const float*)d_in[3];
    const float* b2 = (const float*)d_in[4];
    float* out = (float*)d_out;

    float*    w1tb    = (float*)d_ws;                              // 1,605,632 B
    uint32_t* masks_g = (uint32_t*)((char*)d_ws + 1605632);        // 33,554,432 B

    k0_wtrans<<<dim3(392), 256, 0, stream>>>(w1, w1tb);
    k1_fc1<<<dim3(B_ROWS / (K1_R * 2)), 256, 0, stream>>>(x, w1tb, b1, masks_g);
    k2_fc2<<<dim3((B_ROWS + K2_RPB - 1) / K2_RPB), 256, 0, stream>>>(masks_g, w2, b2, out);
}